// Round 1
// baseline (212.145 us; speedup 1.0000x reference)
//
#include <hip/hip_runtime.h>

#define NB 8
#define IC 64
#define NC 64
#define H 56
#define W 56
#define HW (H*W)

__global__ __launch_bounds__(256) void geom_kernel(
    const float* __restrict__ x,     // (B, IC, H, W)
    const float* __restrict__ geo,   // (C, IC, 2, 3)
    const float* __restrict__ lin,   // (C, IC)
    const float* __restrict__ boxp,  // (C, 2, 3)
    float* __restrict__ out)         // (B, C, H, W)
{
    const int c = blockIdx.x;
    const int p = blockIdx.y * blockDim.x + threadIdx.x;
    if (p >= HW) return;
    const int h = p / W;
    const int w = p - h * W;
    const float xs = 2.0f * ((float)w + 0.5f) / (float)W - 1.0f;
    const float ys = 2.0f * ((float)h + 0.5f) / (float)H - 1.0f;

    float acc[NB];
    #pragma unroll
    for (int b = 0; b < NB; ++b) acc[b] = 0.f;

    const float* gp = geo + c * IC * 6;
    const float* lc = lin + c * IC;

    for (int ic = 0; ic < IC; ++ic) {
        const float t00 = gp[ic*6+0], t01 = gp[ic*6+1], t02 = gp[ic*6+2];
        const float t10 = gp[ic*6+3], t11 = gp[ic*6+4], t12 = gp[ic*6+5];
        const float l = lc[ic];
        const float gx = t00*xs + t01*ys + t02;
        const float gy = t10*xs + t11*ys + t12;
        const float ixf = ((gx + 1.f)*(float)W - 1.f) * 0.5f;
        const float iyf = ((gy + 1.f)*(float)H - 1.f) * 0.5f;
        const float ix0 = floorf(ixf), iy0 = floorf(iyf);
        const float fx = ixf - ix0, fy = iyf - iy0;

        const int cx0 = (int)ix0, cy0 = (int)iy0;
        const int cx1 = cx0 + 1,  cy1 = cy0 + 1;
        const bool vx0 = (cx0 >= 0) && (cx0 <= W-1);
        const bool vx1 = (cx1 >= 0) && (cx1 <= W-1);
        const bool vy0 = (cy0 >= 0) && (cy0 <= H-1);
        const bool vy1 = (cy1 >= 0) && (cy1 <= H-1);

        const float wx0 = 1.f - fx, wx1 = fx;
        const float wy0 = 1.f - fy, wy1 = fy;
        // fold linComb + validity into the 4 corner weights
        const float w00 = wx0*wy0 * ((vx0 && vy0) ? l : 0.f);
        const float w01 = wx0*wy1 * ((vx0 && vy1) ? l : 0.f);
        const float w10 = wx1*wy0 * ((vx1 && vy0) ? l : 0.f);
        const float w11 = wx1*wy1 * ((vx1 && vy1) ? l : 0.f);

        const int icx0 = min(max(cx0, 0), W-1);
        const int icx1 = min(max(cx1, 0), W-1);
        const int icy0 = min(max(cy0, 0), H-1);
        const int icy1 = min(max(cy1, 0), H-1);
        const int i00 = icy0*W + icx0;
        const int i01 = icy1*W + icx0;
        const int i10 = icy0*W + icx1;
        const int i11 = icy1*W + icx1;

        const float* xp = x + ic * HW;
        #pragma unroll
        for (int b = 0; b < NB; ++b) {
            const float* xb = xp + (size_t)b * IC * HW;
            acc[b] += w00*xb[i00] + w01*xb[i01] + w10*xb[i10] + w11*xb[i11];
        }
    }

    // box coverage factor (per c,p)
    float box;
    {
        const float* bp = boxp + c*6;
        const float t00=bp[0], t01=bp[1], t02=bp[2];
        const float t10=bp[3], t11=bp[4], t12=bp[5];
        const float gx = t00*xs + t01*ys + t02;
        const float gy = t10*xs + t11*ys + t12;
        const float ixf = ((gx + 1.f)*(float)W - 1.f) * 0.5f;
        const float iyf = ((gy + 1.f)*(float)H - 1.f) * 0.5f;
        const float ix0 = floorf(ixf), iy0 = floorf(iyf);
        const float fx = ixf - ix0, fy = iyf - iy0;
        const int cx0 = (int)ix0, cy0 = (int)iy0;
        const int cx1 = cx0 + 1,  cy1 = cy0 + 1;
        const bool vx0 = (cx0 >= 0) && (cx0 < W);
        const bool vx1 = (cx1 >= 0) && (cx1 < W);
        const bool vy0 = (cy0 >= 0) && (cy0 < H);
        const bool vy1 = (cy1 >= 0) && (cy1 < H);
        box = (1.f-fx)*(1.f-fy)*((vx0 && vy0) ? 1.f : 0.f)
            + (1.f-fx)*fy     *((vx0 && vy1) ? 1.f : 0.f)
            + fx*(1.f-fy)     *((vx1 && vy0) ? 1.f : 0.f)
            + fx*fy           *((vx1 && vy1) ? 1.f : 0.f);
    }

    #pragma unroll
    for (int b = 0; b < NB; ++b) {
        out[((size_t)b*NC + c)*HW + p] = acc[b] * box;
    }
}

extern "C" void kernel_launch(void* const* d_in, const int* in_sizes, int n_in,
                              void* d_out, int out_size, void* d_ws, size_t ws_size,
                              hipStream_t stream) {
    const float* x    = (const float*)d_in[0];
    const float* geo  = (const float*)d_in[1];
    const float* lin  = (const float*)d_in[2];
    const float* boxp = (const float*)d_in[3];
    float* out = (float*)d_out;

    dim3 grid(NC, (HW + 255) / 256);
    dim3 block(256);
    hipLaunchKernelGGL(geom_kernel, grid, block, 0, stream, x, geo, lin, boxp, out);
}

// Round 2
// 83.055 us; speedup vs baseline: 2.5543x; 2.5543x over previous
//
#include <hip/hip_runtime.h>

#define NB 8
#define ICN 64
#define NC 64
#define H 56
#define W 56
#define HW (H*W)

// ---------- pre-pass: x (B, IC, HW) -> xt (IC, HW, B) ----------
__global__ __launch_bounds__(256) void transpose_kernel(
    const float* __restrict__ x, float* __restrict__ xt)
{
    const int id = blockIdx.x * 256 + threadIdx.x;   // ic*HW + px
    if (id >= ICN * HW) return;
    float v[NB];
    #pragma unroll
    for (int b = 0; b < NB; ++b) v[b] = x[(size_t)b * ICN * HW + id];
    float4* dst = (float4*)(xt + (size_t)id * NB);
    dst[0] = make_float4(v[0], v[1], v[2], v[3]);
    dst[1] = make_float4(v[4], v[5], v[6], v[7]);
}

// ---------- main: thread owns (c, p, batch-half), 4 accumulators ----------
__global__ __launch_bounds__(448) void geom_t_kernel(
    const float* __restrict__ xt,    // (IC, HW, B)
    const float* __restrict__ geo,   // (C, IC, 2, 3)
    const float* __restrict__ lin,   // (C, IC)
    const float* __restrict__ boxp,  // (C, 2, 3)
    float* __restrict__ out)         // (B, C, H, W)
{
    const int c  = blockIdx.x;
    const int p  = blockIdx.y * 448 + threadIdx.x;   // 7 blocks * 448 = 3136 exactly
    const int bh = blockIdx.z;                        // batch half: 0 -> b0..3, 1 -> b4..7
    const int h = p / W;
    const int w = p - h * W;
    const float xs = 2.0f * ((float)w + 0.5f) / (float)W - 1.0f;
    const float ys = 2.0f * ((float)h + 0.5f) / (float)H - 1.0f;

    float4 acc = make_float4(0.f, 0.f, 0.f, 0.f);

    const float* gp = geo + c * ICN * 6;
    const float* lc = lin + c * ICN;
    const float* xtb = xt + bh * 4;                   // half offset in floats (16B)

    for (int ic = 0; ic < ICN; ++ic) {
        const float t00 = gp[ic*6+0], t01 = gp[ic*6+1], t02 = gp[ic*6+2];
        const float t10 = gp[ic*6+3], t11 = gp[ic*6+4], t12 = gp[ic*6+5];
        const float l = lc[ic];
        const float gx = t00*xs + t01*ys + t02;
        const float gy = t10*xs + t11*ys + t12;
        const float ixf = ((gx + 1.f)*(float)W - 1.f) * 0.5f;
        const float iyf = ((gy + 1.f)*(float)H - 1.f) * 0.5f;
        const float ix0 = floorf(ixf), iy0 = floorf(iyf);
        const float fx = ixf - ix0, fy = iyf - iy0;

        const int cx0 = (int)ix0, cy0 = (int)iy0;
        const int cx1 = cx0 + 1,  cy1 = cy0 + 1;
        const bool vx0 = (cx0 >= 0) && (cx0 <= W-1);
        const bool vx1 = (cx1 >= 0) && (cx1 <= W-1);
        const bool vy0 = (cy0 >= 0) && (cy0 <= H-1);
        const bool vy1 = (cy1 >= 0) && (cy1 <= H-1);

        const float wx0 = 1.f - fx, wx1 = fx;
        const float wy0 = 1.f - fy, wy1 = fy;
        const float w00 = wx0*wy0 * ((vx0 && vy0) ? l : 0.f);
        const float w01 = wx0*wy1 * ((vx0 && vy1) ? l : 0.f);
        const float w10 = wx1*wy0 * ((vx1 && vy0) ? l : 0.f);
        const float w11 = wx1*wy1 * ((vx1 && vy1) ? l : 0.f);

        const int icx0 = min(max(cx0, 0), W-1);
        const int icx1 = min(max(cx1, 0), W-1);
        const int icy0 = min(max(cy0, 0), H-1);
        const int icy1 = min(max(cy1, 0), H-1);
        const int i00 = icy0*W + icx0;
        const int i01 = icy1*W + icx0;
        const int i10 = icy0*W + icx1;
        const int i11 = icy1*W + icx1;

        const float* base = xtb + (size_t)ic * HW * NB;
        const float4 v00 = *(const float4*)(base + (size_t)i00 * NB);
        const float4 v10 = *(const float4*)(base + (size_t)i10 * NB);
        const float4 v01 = *(const float4*)(base + (size_t)i01 * NB);
        const float4 v11 = *(const float4*)(base + (size_t)i11 * NB);

        acc.x += w00*v00.x + w10*v10.x + w01*v01.x + w11*v11.x;
        acc.y += w00*v00.y + w10*v10.y + w01*v01.y + w11*v11.y;
        acc.z += w00*v00.z + w10*v10.z + w01*v01.z + w11*v11.z;
        acc.w += w00*v00.w + w10*v10.w + w01*v01.w + w11*v11.w;
    }

    // box coverage factor (per c,p)
    float box;
    {
        const float* bp = boxp + c*6;
        const float gx = bp[0]*xs + bp[1]*ys + bp[2];
        const float gy = bp[3]*xs + bp[4]*ys + bp[5];
        const float ixf = ((gx + 1.f)*(float)W - 1.f) * 0.5f;
        const float iyf = ((gy + 1.f)*(float)H - 1.f) * 0.5f;
        const float ix0 = floorf(ixf), iy0 = floorf(iyf);
        const float fx = ixf - ix0, fy = iyf - iy0;
        const int cx0 = (int)ix0, cy0 = (int)iy0;
        const int cx1 = cx0 + 1,  cy1 = cy0 + 1;
        const bool vx0 = (cx0 >= 0) && (cx0 < W);
        const bool vx1 = (cx1 >= 0) && (cx1 < W);
        const bool vy0 = (cy0 >= 0) && (cy0 < H);
        const bool vy1 = (cy1 >= 0) && (cy1 < H);
        box = (1.f-fx)*(1.f-fy)*((vx0 && vy0) ? 1.f : 0.f)
            + (1.f-fx)*fy     *((vx0 && vy1) ? 1.f : 0.f)
            + fx*(1.f-fy)     *((vx1 && vy0) ? 1.f : 0.f)
            + fx*fy           *((vx1 && vy1) ? 1.f : 0.f);
    }

    const int b0 = bh * 4;
    out[((size_t)(b0+0)*NC + c)*HW + p] = acc.x * box;
    out[((size_t)(b0+1)*NC + c)*HW + p] = acc.y * box;
    out[((size_t)(b0+2)*NC + c)*HW + p] = acc.z * box;
    out[((size_t)(b0+3)*NC + c)*HW + p] = acc.w * box;
}

// ---------- fallback (round-1 kernel, no workspace needed) ----------
__global__ __launch_bounds__(256) void geom_kernel(
    const float* __restrict__ x, const float* __restrict__ geo,
    const float* __restrict__ lin, const float* __restrict__ boxp,
    float* __restrict__ out)
{
    const int c = blockIdx.x;
    const int p = blockIdx.y * blockDim.x + threadIdx.x;
    if (p >= HW) return;
    const int h = p / W;
    const int w = p - h * W;
    const float xs = 2.0f * ((float)w + 0.5f) / (float)W - 1.0f;
    const float ys = 2.0f * ((float)h + 0.5f) / (float)H - 1.0f;

    float acc[NB];
    #pragma unroll
    for (int b = 0; b < NB; ++b) acc[b] = 0.f;

    const float* gp = geo + c * ICN * 6;
    const float* lc = lin + c * ICN;

    for (int ic = 0; ic < ICN; ++ic) {
        const float t00 = gp[ic*6+0], t01 = gp[ic*6+1], t02 = gp[ic*6+2];
        const float t10 = gp[ic*6+3], t11 = gp[ic*6+4], t12 = gp[ic*6+5];
        const float l = lc[ic];
        const float gx = t00*xs + t01*ys + t02;
        const float gy = t10*xs + t11*ys + t12;
        const float ixf = ((gx + 1.f)*(float)W - 1.f) * 0.5f;
        const float iyf = ((gy + 1.f)*(float)H - 1.f) * 0.5f;
        const float ix0 = floorf(ixf), iy0 = floorf(iyf);
        const float fx = ixf - ix0, fy = iyf - iy0;
        const int cx0 = (int)ix0, cy0 = (int)iy0;
        const int cx1 = cx0 + 1,  cy1 = cy0 + 1;
        const bool vx0 = (cx0 >= 0) && (cx0 <= W-1);
        const bool vx1 = (cx1 >= 0) && (cx1 <= W-1);
        const bool vy0 = (cy0 >= 0) && (cy0 <= H-1);
        const bool vy1 = (cy1 >= 0) && (cy1 <= H-1);
        const float wx0 = 1.f - fx, wx1 = fx;
        const float wy0 = 1.f - fy, wy1 = fy;
        const float w00 = wx0*wy0 * ((vx0 && vy0) ? l : 0.f);
        const float w01 = wx0*wy1 * ((vx0 && vy1) ? l : 0.f);
        const float w10 = wx1*wy0 * ((vx1 && vy0) ? l : 0.f);
        const float w11 = wx1*wy1 * ((vx1 && vy1) ? l : 0.f);
        const int icx0 = min(max(cx0, 0), W-1);
        const int icx1 = min(max(cx1, 0), W-1);
        const int icy0 = min(max(cy0, 0), H-1);
        const int icy1 = min(max(cy1, 0), H-1);
        const int i00 = icy0*W + icx0;
        const int i01 = icy1*W + icx0;
        const int i10 = icy0*W + icx1;
        const int i11 = icy1*W + icx1;
        const float* xp = x + ic * HW;
        #pragma unroll
        for (int b = 0; b < NB; ++b) {
            const float* xb = xp + (size_t)b * ICN * HW;
            acc[b] += w00*xb[i00] + w01*xb[i01] + w10*xb[i10] + w11*xb[i11];
        }
    }

    float box;
    {
        const float* bp = boxp + c*6;
        const float gx = bp[0]*xs + bp[1]*ys + bp[2];
        const float gy = bp[3]*xs + bp[4]*ys + bp[5];
        const float ixf = ((gx + 1.f)*(float)W - 1.f) * 0.5f;
        const float iyf = ((gy + 1.f)*(float)H - 1.f) * 0.5f;
        const float ix0 = floorf(ixf), iy0 = floorf(iyf);
        const float fx = ixf - ix0, fy = iyf - iy0;
        const int cx0 = (int)ix0, cy0 = (int)iy0;
        const int cx1 = cx0 + 1,  cy1 = cy0 + 1;
        const bool vx0 = (cx0 >= 0) && (cx0 < W);
        const bool vx1 = (cx1 >= 0) && (cx1 < W);
        const bool vy0 = (cy0 >= 0) && (cy0 < H);
        const bool vy1 = (cy1 >= 0) && (cy1 < H);
        box = (1.f-fx)*(1.f-fy)*((vx0 && vy0) ? 1.f : 0.f)
            + (1.f-fx)*fy     *((vx0 && vy1) ? 1.f : 0.f)
            + fx*(1.f-fy)     *((vx1 && vy0) ? 1.f : 0.f)
            + fx*fy           *((vx1 && vy1) ? 1.f : 0.f);
    }
    #pragma unroll
    for (int b = 0; b < NB; ++b)
        out[((size_t)b*NC + c)*HW + p] = acc[b] * box;
}

extern "C" void kernel_launch(void* const* d_in, const int* in_sizes, int n_in,
                              void* d_out, int out_size, void* d_ws, size_t ws_size,
                              hipStream_t stream) {
    const float* x    = (const float*)d_in[0];
    const float* geo  = (const float*)d_in[1];
    const float* lin  = (const float*)d_in[2];
    const float* boxp = (const float*)d_in[3];
    float* out = (float*)d_out;

    const size_t xt_bytes = (size_t)ICN * HW * NB * sizeof(float);  // ~6.4 MB
    if (ws_size >= xt_bytes) {
        float* xt = (float*)d_ws;
        hipLaunchKernelGGL(transpose_kernel, dim3((ICN*HW + 255)/256), dim3(256),
                           0, stream, x, xt);
        hipLaunchKernelGGL(geom_t_kernel, dim3(NC, 7, 2), dim3(448),
                           0, stream, xt, geo, lin, boxp, out);
    } else {
        hipLaunchKernelGGL(geom_kernel, dim3(NC, (HW + 255)/256), dim3(256),
                           0, stream, x, geo, lin, boxp, out);
    }
}

// Round 3
// 64.938 us; speedup vs baseline: 3.2669x; 1.2790x over previous
//
#include <hip/hip_runtime.h>

#define NB 8
#define ICN 64
#define NC 64
#define H 56
#define W 56
#define HW (H*W)
#define PH 58
#define PW 58
#define PHW (PH*PW)

typedef __attribute__((ext_vector_type(8))) _Float16 half8;

// ---------- pre-pass: x (B, IC, HW) fp32 -> xt (IC, 58, 58, B) fp16, zero-padded ----------
__global__ __launch_bounds__(256) void transpose_pad_kernel(
    const float* __restrict__ x, _Float16* __restrict__ xt)
{
    const int id = blockIdx.x * 256 + threadIdx.x;   // ic*HW + px
    if (id >= ICN * HW) return;
    const int ic = id / HW;
    const int p  = id - ic * HW;
    const int h  = p / W;
    const int w  = p - h * W;
    half8 v;
    #pragma unroll
    for (int b = 0; b < NB; ++b)
        v[b] = (_Float16)x[(size_t)b * ICN * HW + id];
    const size_t dst = ((size_t)ic * PHW + (size_t)(h + 1) * PW + (w + 1)) * NB;
    *(half8*)(xt + dst) = v;
}

// ---------- main: thread owns (c, p), all 8 batches; padded fp16 gathers ----------
__global__ __launch_bounds__(64) void geom_h_kernel(
    const _Float16* __restrict__ xt, // (IC, 58, 58, B)
    const float* __restrict__ geo,   // (C, IC, 2, 3)
    const float* __restrict__ lin,   // (C, IC)
    const float* __restrict__ boxp,  // (C, 2, 3)
    float* __restrict__ out)         // (B, C, H, W)
{
    const int c = blockIdx.x;
    const int p = blockIdx.y * 64 + threadIdx.x;     // 49 blocks * 64 = 3136 exactly
    const int h = p / W;
    const int w = p - h * W;
    const float xs = 2.0f * ((float)w + 0.5f) / (float)W - 1.0f;
    const float ys = 2.0f * ((float)h + 0.5f) / (float)H - 1.0f;

    float acc[NB];
    #pragma unroll
    for (int b = 0; b < NB; ++b) acc[b] = 0.f;

    const float* gp = geo + c * ICN * 6;
    const float* lc = lin + c * ICN;

    for (int ic = 0; ic < ICN; ++ic) {
        const float t00 = gp[ic*6+0], t01 = gp[ic*6+1], t02 = gp[ic*6+2];
        const float t10 = gp[ic*6+3], t11 = gp[ic*6+4], t12 = gp[ic*6+5];
        const float l = lc[ic];
        const float gx = t00*xs + t01*ys + t02;
        const float gy = t10*xs + t11*ys + t12;
        const float ixf = ((gx + 1.f)*(float)W - 1.f) * 0.5f;
        const float iyf = ((gy + 1.f)*(float)H - 1.f) * 0.5f;

        // clamped floor; pad (zeros) absorbs invalid corners
        const float fcx0 = fminf(fmaxf(floorf(ixf), -1.f), 55.f);   // med3
        const float fcy0 = fminf(fmaxf(floorf(iyf), -1.f), 55.f);
        const float wx0 = fmaxf(0.f, 1.f - fabsf(ixf - fcx0));
        const float wx1 = fmaxf(0.f, 1.f - fabsf(ixf - (fcx0 + 1.f)));
        const float wy0 = fmaxf(0.f, 1.f - fabsf(iyf - fcy0));
        const float wy1 = fmaxf(0.f, 1.f - fabsf(iyf - (fcy0 + 1.f)));

        const float wy0l = wy0 * l, wy1l = wy1 * l;
        const float w00 = wx0 * wy0l;
        const float w01 = wx0 * wy1l;
        const float w10 = wx1 * wy0l;
        const float w11 = wx1 * wy1l;

        const int icx0 = (int)fcx0, icy0 = (int)fcy0;
        const int i00 = (icy0 + 1) * PW + (icx0 + 1);   // padded index
        const _Float16* base = xt + ((size_t)ic * PHW + i00) * NB;

        const half8 v00 = *(const half8*)(base);
        const half8 v10 = *(const half8*)(base + NB);           // +1 px  (+16B)
        const half8 v01 = *(const half8*)(base + PW * NB);      // +1 row (+928B)
        const half8 v11 = *(const half8*)(base + (PW + 1) * NB);// (+944B)

        #pragma unroll
        for (int b = 0; b < NB; ++b) {
            acc[b] += w00 * (float)v00[b] + w10 * (float)v10[b]
                    + w01 * (float)v01[b] + w11 * (float)v11[b];
        }
    }

    // box coverage factor (per c,p)
    float box;
    {
        const float* bp = boxp + c*6;
        const float gx = bp[0]*xs + bp[1]*ys + bp[2];
        const float gy = bp[3]*xs + bp[4]*ys + bp[5];
        const float ixf = ((gx + 1.f)*(float)W - 1.f) * 0.5f;
        const float iyf = ((gy + 1.f)*(float)H - 1.f) * 0.5f;
        const float ix0 = floorf(ixf), iy0 = floorf(iyf);
        const float fx = ixf - ix0, fy = iyf - iy0;
        const int cx0 = (int)ix0, cy0 = (int)iy0;
        const int cx1 = cx0 + 1,  cy1 = cy0 + 1;
        const bool vx0 = (cx0 >= 0) && (cx0 < W);
        const bool vx1 = (cx1 >= 0) && (cx1 < W);
        const bool vy0 = (cy0 >= 0) && (cy0 < H);
        const bool vy1 = (cy1 >= 0) && (cy1 < H);
        box = (1.f-fx)*(1.f-fy)*((vx0 && vy0) ? 1.f : 0.f)
            + (1.f-fx)*fy     *((vx0 && vy1) ? 1.f : 0.f)
            + fx*(1.f-fy)     *((vx1 && vy0) ? 1.f : 0.f)
            + fx*fy           *((vx1 && vy1) ? 1.f : 0.f);
    }

    #pragma unroll
    for (int b = 0; b < NB; ++b)
        out[((size_t)b*NC + c)*HW + p] = acc[b] * box;
}

// ---------- fallback (round-1 kernel, no workspace needed) ----------
__global__ __launch_bounds__(256) void geom_kernel(
    const float* __restrict__ x, const float* __restrict__ geo,
    const float* __restrict__ lin, const float* __restrict__ boxp,
    float* __restrict__ out)
{
    const int c = blockIdx.x;
    const int p = blockIdx.y * blockDim.x + threadIdx.x;
    if (p >= HW) return;
    const int h = p / W;
    const int w = p - h * W;
    const float xs = 2.0f * ((float)w + 0.5f) / (float)W - 1.0f;
    const float ys = 2.0f * ((float)h + 0.5f) / (float)H - 1.0f;

    float acc[NB];
    #pragma unroll
    for (int b = 0; b < NB; ++b) acc[b] = 0.f;

    const float* gp = geo + c * ICN * 6;
    const float* lc = lin + c * ICN;

    for (int ic = 0; ic < ICN; ++ic) {
        const float t00 = gp[ic*6+0], t01 = gp[ic*6+1], t02 = gp[ic*6+2];
        const float t10 = gp[ic*6+3], t11 = gp[ic*6+4], t12 = gp[ic*6+5];
        const float l = lc[ic];
        const float gx = t00*xs + t01*ys + t02;
        const float gy = t10*xs + t11*ys + t12;
        const float ixf = ((gx + 1.f)*(float)W - 1.f) * 0.5f;
        const float iyf = ((gy + 1.f)*(float)H - 1.f) * 0.5f;
        const float ix0 = floorf(ixf), iy0 = floorf(iyf);
        const float fx = ixf - ix0, fy = iyf - iy0;
        const int cx0 = (int)ix0, cy0 = (int)iy0;
        const int cx1 = cx0 + 1,  cy1 = cy0 + 1;
        const bool vx0 = (cx0 >= 0) && (cx0 <= W-1);
        const bool vx1 = (cx1 >= 0) && (cx1 <= W-1);
        const bool vy0 = (cy0 >= 0) && (cy0 <= H-1);
        const bool vy1 = (cy1 >= 0) && (cy1 <= H-1);
        const float wx0 = 1.f - fx, wx1 = fx;
        const float wy0 = 1.f - fy, wy1 = fy;
        const float w00 = wx0*wy0 * ((vx0 && vy0) ? l : 0.f);
        const float w01 = wx0*wy1 * ((vx0 && vy1) ? l : 0.f);
        const float w10 = wx1*wy0 * ((vx1 && vy0) ? l : 0.f);
        const float w11 = wx1*wy1 * ((vx1 && vy1) ? l : 0.f);
        const int icx0 = min(max(cx0, 0), W-1);
        const int icx1 = min(max(cx1, 0), W-1);
        const int icy0 = min(max(cy0, 0), H-1);
        const int icy1 = min(max(cy1, 0), H-1);
        const int i00 = icy0*W + icx0;
        const int i01 = icy1*W + icx0;
        const int i10 = icy0*W + icx1;
        const int i11 = icy1*W + icx1;
        const float* xp = x + ic * HW;
        #pragma unroll
        for (int b = 0; b < NB; ++b) {
            const float* xb = xp + (size_t)b * ICN * HW;
            acc[b] += w00*xb[i00] + w01*xb[i01] + w10*xb[i10] + w11*xb[i11];
        }
    }

    float box;
    {
        const float* bp = boxp + c*6;
        const float gx = bp[0]*xs + bp[1]*ys + bp[2];
        const float gy = bp[3]*xs + bp[4]*ys + bp[5];
        const float ixf = ((gx + 1.f)*(float)W - 1.f) * 0.5f;
        const float iyf = ((gy + 1.f)*(float)H - 1.f) * 0.5f;
        const float ix0 = floorf(ixf), iy0 = floorf(iyf);
        const float fx = ixf - ix0, fy = iyf - iy0;
        const int cx0 = (int)ix0, cy0 = (int)iy0;
        const int cx1 = cx0 + 1,  cy1 = cy0 + 1;
        const bool vx0 = (cx0 >= 0) && (cx0 < W);
        const bool vx1 = (cx1 >= 0) && (cx1 < W);
        const bool vy0 = (cy0 >= 0) && (cy0 < H);
        const bool vy1 = (cy1 >= 0) && (cy1 < H);
        box = (1.f-fx)*(1.f-fy)*((vx0 && vy0) ? 1.f : 0.f)
            + (1.f-fx)*fy     *((vx0 && vy1) ? 1.f : 0.f)
            + fx*(1.f-fy)     *((vx1 && vy0) ? 1.f : 0.f)
            + fx*fy           *((vx1 && vy1) ? 1.f : 0.f);
    }
    #pragma unroll
    for (int b = 0; b < NB; ++b)
        out[((size_t)b*NC + c)*HW + p] = acc[b] * box;
}

extern "C" void kernel_launch(void* const* d_in, const int* in_sizes, int n_in,
                              void* d_out, int out_size, void* d_ws, size_t ws_size,
                              hipStream_t stream) {
    const float* x    = (const float*)d_in[0];
    const float* geo  = (const float*)d_in[1];
    const float* lin  = (const float*)d_in[2];
    const float* boxp = (const float*)d_in[3];
    float* out = (float*)d_out;

    const size_t xt_bytes = (size_t)ICN * PHW * NB * sizeof(_Float16);  // ~3.4 MB
    if (ws_size >= xt_bytes) {
        _Float16* xt = (_Float16*)d_ws;
        hipMemsetAsync(d_ws, 0, xt_bytes, stream);   // zero the pad borders
        hipLaunchKernelGGL(transpose_pad_kernel, dim3((ICN*HW + 255)/256), dim3(256),
                           0, stream, x, xt);
        hipLaunchKernelGGL(geom_h_kernel, dim3(NC, 49), dim3(64),
                           0, stream, xt, geo, lin, boxp, out);
    } else {
        hipLaunchKernelGGL(geom_kernel, dim3(NC, (HW + 255)/256), dim3(256),
                           0, stream, x, geo, lin, boxp, out);
    }
}

// Round 4
// 55.014 us; speedup vs baseline: 3.8562x; 1.1804x over previous
//
#include <hip/hip_runtime.h>

#define NB 8
#define ICN 64
#define NC 64
#define H 56
#define W 56
#define HW (H*W)
#define PH 58
#define PW 58
#define PHW (PH*PW)   // 3364

typedef __attribute__((ext_vector_type(8))) _Float16 half8;

// ---------- prep: fold sampling transform per (c,ic) ----------
// ixf = Ax*w + Bx*h + Cx ; iyf = Ay*w + By*h + Cy ; plus linComb l.
// Derivation: xs=(w+0.5)/28-1, ix=28*gx+27.5 with gx=t00*xs+t01*ys+t02
//  -> Ax=t00, Bx=t01, Cx=-27.5*(t00+t01)+28*t02+27.5 (W=H=56).
__global__ __launch_bounds__(256) void prep_kernel(
    const float* __restrict__ geo, const float* __restrict__ lin,
    float* __restrict__ prm)
{
    const int i = blockIdx.x * 256 + threadIdx.x;   // c*ICN + ic
    if (i >= NC * ICN) return;
    const float t00 = geo[i*6+0], t01 = geo[i*6+1], t02 = geo[i*6+2];
    const float t10 = geo[i*6+3], t11 = geo[i*6+4], t12 = geo[i*6+5];
    prm[i*8+0] = t00;
    prm[i*8+1] = t01;
    prm[i*8+2] = -27.5f*(t00+t01) + 28.f*t02 + 27.5f;
    prm[i*8+3] = t10;
    prm[i*8+4] = t11;
    prm[i*8+5] = -27.5f*(t10+t11) + 28.f*t12 + 27.5f;
    prm[i*8+6] = lin[i];
    prm[i*8+7] = 0.f;
}

// ---------- pre-pass: x (B, IC, HW) fp32 -> xt (IC, 58, 58, B) fp16, zero-padded ----------
__global__ __launch_bounds__(256) void transpose_pad_kernel(
    const float* __restrict__ x, _Float16* __restrict__ xt)
{
    const int id = blockIdx.x * 256 + threadIdx.x;   // ic*HW + px
    if (id >= ICN * HW) return;
    const int ic = id / HW;
    const int p  = id - ic * HW;
    const int h  = p / W;
    const int w  = p - h * W;
    half8 v;
    #pragma unroll
    for (int b = 0; b < NB; ++b)
        v[b] = (_Float16)x[(size_t)b * ICN * HW + id];
    const size_t dst = ((size_t)ic * PHW + (size_t)(h + 1) * PW + (w + 1)) * NB;
    *(half8*)(xt + dst) = v;
}

// ---------- main: thread owns (c,p), all 8 batches; packed fp16 accumulate ----------
__global__ __launch_bounds__(64) void geom_h_kernel(
    const _Float16* __restrict__ xt, // (IC, 58, 58, B)
    const float* __restrict__ prm,   // (C, IC, 8) folded params
    const float* __restrict__ boxp,  // (C, 2, 3)
    float* __restrict__ out)         // (B, C, H, W)
{
    const int c = blockIdx.x;
    const int p = blockIdx.y * 64 + threadIdx.x;     // 49 blocks * 64 = 3136 exactly
    const int h = p / W;
    const int w = p - h * W;
    const float wf = (float)w, hf = (float)h;

    float acc[NB];
    #pragma unroll
    for (int b = 0; b < NB; ++b) acc[b] = 0.f;

    const float* pp = prm + (size_t)c * ICN * 8;

    for (int icc = 0; icc < ICN; icc += 4) {
        half8 hacc;
        #pragma unroll
        for (int b = 0; b < NB; ++b) hacc[b] = (_Float16)0.f;

        #pragma unroll
        for (int k = 0; k < 4; ++k) {
            const float* q = pp + (icc + k) * 8;     // uniform -> s_load
            const float ixf = fmaf(q[0], wf, fmaf(q[1], hf, q[2]));
            const float iyf = fmaf(q[3], wf, fmaf(q[4], hf, q[5]));
            const float l   = q[6];

            const float fcx0 = fminf(fmaxf(floorf(ixf), -1.f), 55.f);
            const float fcy0 = fminf(fmaxf(floorf(iyf), -1.f), 55.f);
            const float wx0 = fmaxf(0.f, 1.f - fabsf(ixf - fcx0));
            const float wx1 = fmaxf(0.f, 1.f - fabsf(ixf - fcx0 - 1.f));
            const float wy0 = fmaxf(0.f, 1.f - fabsf(iyf - fcy0));
            const float wy1 = fmaxf(0.f, 1.f - fabsf(iyf - fcy0 - 1.f));
            const float wy0l = wy0 * l, wy1l = wy1 * l;

            const _Float16 hw00 = (_Float16)(wx0 * wy0l);
            const _Float16 hw10 = (_Float16)(wx1 * wy0l);
            const _Float16 hw01 = (_Float16)(wx0 * wy1l);
            const _Float16 hw11 = (_Float16)(wx1 * wy1l);

            const int i00 = ((int)fcy0) * PW + (int)fcx0 + (PW + 1); // padded index
            const _Float16* base = xt + ((size_t)(icc + k) * PHW + i00) * NB;

            const half8 v00 = *(const half8*)(base);
            const half8 v10 = *(const half8*)(base + NB);            // +16B
            const half8 v01 = *(const half8*)(base + PW * NB);       // +928B
            const half8 v11 = *(const half8*)(base + (PW + 1) * NB); // +944B

            hacc += v00 * hw00 + v10 * hw10 + v01 * hw01 + v11 * hw11;
        }

        #pragma unroll
        for (int b = 0; b < NB; ++b) acc[b] += (float)hacc[b];
    }

    // box coverage factor (per c,p)
    float box;
    {
        const float* bp = boxp + c*6;
        const float xs = 2.0f * (wf + 0.5f) / (float)W - 1.0f;
        const float ys = 2.0f * (hf + 0.5f) / (float)H - 1.0f;
        const float gx = bp[0]*xs + bp[1]*ys + bp[2];
        const float gy = bp[3]*xs + bp[4]*ys + bp[5];
        const float ixf = ((gx + 1.f)*(float)W - 1.f) * 0.5f;
        const float iyf = ((gy + 1.f)*(float)H - 1.f) * 0.5f;
        const float ix0 = floorf(ixf), iy0 = floorf(iyf);
        const float fx = ixf - ix0, fy = iyf - iy0;
        const int cx0 = (int)ix0, cy0 = (int)iy0;
        const int cx1 = cx0 + 1,  cy1 = cy0 + 1;
        const bool vx0 = (cx0 >= 0) && (cx0 < W);
        const bool vx1 = (cx1 >= 0) && (cx1 < W);
        const bool vy0 = (cy0 >= 0) && (cy0 < H);
        const bool vy1 = (cy1 >= 0) && (cy1 < H);
        box = (1.f-fx)*(1.f-fy)*((vx0 && vy0) ? 1.f : 0.f)
            + (1.f-fx)*fy     *((vx0 && vy1) ? 1.f : 0.f)
            + fx*(1.f-fy)     *((vx1 && vy0) ? 1.f : 0.f)
            + fx*fy           *((vx1 && vy1) ? 1.f : 0.f);
    }

    #pragma unroll
    for (int b = 0; b < NB; ++b)
        out[((size_t)b*NC + c)*HW + p] = acc[b] * box;
}

// ---------- fallback (round-1 kernel, no workspace needed) ----------
__global__ __launch_bounds__(256) void geom_kernel(
    const float* __restrict__ x, const float* __restrict__ geo,
    const float* __restrict__ lin, const float* __restrict__ boxp,
    float* __restrict__ out)
{
    const int c = blockIdx.x;
    const int p = blockIdx.y * blockDim.x + threadIdx.x;
    if (p >= HW) return;
    const int h = p / W;
    const int w = p - h * W;
    const float xs = 2.0f * ((float)w + 0.5f) / (float)W - 1.0f;
    const float ys = 2.0f * ((float)h + 0.5f) / (float)H - 1.0f;

    float acc[NB];
    #pragma unroll
    for (int b = 0; b < NB; ++b) acc[b] = 0.f;

    const float* gp = geo + c * ICN * 6;
    const float* lc = lin + c * ICN;

    for (int ic = 0; ic < ICN; ++ic) {
        const float t00 = gp[ic*6+0], t01 = gp[ic*6+1], t02 = gp[ic*6+2];
        const float t10 = gp[ic*6+3], t11 = gp[ic*6+4], t12 = gp[ic*6+5];
        const float l = lc[ic];
        const float gx = t00*xs + t01*ys + t02;
        const float gy = t10*xs + t11*ys + t12;
        const float ixf = ((gx + 1.f)*(float)W - 1.f) * 0.5f;
        const float iyf = ((gy + 1.f)*(float)H - 1.f) * 0.5f;
        const float ix0 = floorf(ixf), iy0 = floorf(iyf);
        const float fx = ixf - ix0, fy = iyf - iy0;
        const int cx0 = (int)ix0, cy0 = (int)iy0;
        const int cx1 = cx0 + 1,  cy1 = cy0 + 1;
        const bool vx0 = (cx0 >= 0) && (cx0 <= W-1);
        const bool vx1 = (cx1 >= 0) && (cx1 <= W-1);
        const bool vy0 = (cy0 >= 0) && (cy0 <= H-1);
        const bool vy1 = (cy1 >= 0) && (cy1 <= H-1);
        const float wx0 = 1.f - fx, wx1 = fx;
        const float wy0 = 1.f - fy, wy1 = fy;
        const float w00 = wx0*wy0 * ((vx0 && vy0) ? l : 0.f);
        const float w01 = wx0*wy1 * ((vx0 && vy1) ? l : 0.f);
        const float w10 = wx1*wy0 * ((vx1 && vy0) ? l : 0.f);
        const float w11 = wx1*wy1 * ((vx1 && vy1) ? l : 0.f);
        const int icx0 = min(max(cx0, 0), W-1);
        const int icx1 = min(max(cx1, 0), W-1);
        const int icy0 = min(max(cy0, 0), H-1);
        const int icy1 = min(max(cy1, 0), H-1);
        const int i00 = icy0*W + icx0;
        const int i01 = icy1*W + icx0;
        const int i10 = icy0*W + icx1;
        const int i11 = icy1*W + icx1;
        const float* xp = x + ic * HW;
        #pragma unroll
        for (int b = 0; b < NB; ++b) {
            const float* xb = xp + (size_t)b * ICN * HW;
            acc[b] += w00*xb[i00] + w01*xb[i01] + w10*xb[i10] + w11*xb[i11];
        }
    }

    float box;
    {
        const float* bp = boxp + c*6;
        const float gx = bp[0]*xs + bp[1]*ys + bp[2];
        const float gy = bp[3]*xs + bp[4]*ys + bp[5];
        const float ixf = ((gx + 1.f)*(float)W - 1.f) * 0.5f;
        const float iyf = ((gy + 1.f)*(float)H - 1.f) * 0.5f;
        const float ix0 = floorf(ixf), iy0 = floorf(iyf);
        const float fx = ixf - ix0, fy = iyf - iy0;
        const int cx0 = (int)ix0, cy0 = (int)iy0;
        const int cx1 = cx0 + 1,  cy1 = cy0 + 1;
        const bool vx0 = (cx0 >= 0) && (cx0 < W);
        const bool vx1 = (cx1 >= 0) && (cx1 < W);
        const bool vy0 = (cy0 >= 0) && (cy0 < H);
        const bool vy1 = (cy1 >= 0) && (cy1 < H);
        box = (1.f-fx)*(1.f-fy)*((vx0 && vy0) ? 1.f : 0.f)
            + (1.f-fx)*fy     *((vx0 && vy1) ? 1.f : 0.f)
            + fx*(1.f-fy)     *((vx1 && vy0) ? 1.f : 0.f)
            + fx*fy           *((vx1 && vy1) ? 1.f : 0.f);
    }
    #pragma unroll
    for (int b = 0; b < NB; ++b)
        out[((size_t)b*NC + c)*HW + p] = acc[b] * box;
}

extern "C" void kernel_launch(void* const* d_in, const int* in_sizes, int n_in,
                              void* d_out, int out_size, void* d_ws, size_t ws_size,
                              hipStream_t stream) {
    const float* x    = (const float*)d_in[0];
    const float* geo  = (const float*)d_in[1];
    const float* lin  = (const float*)d_in[2];
    const float* boxp = (const float*)d_in[3];
    float* out = (float*)d_out;

    const size_t xt_bytes  = (size_t)ICN * PHW * NB * sizeof(_Float16); // 3,444,736
    const size_t prm_off   = (xt_bytes + 255) & ~(size_t)255;
    const size_t prm_bytes = (size_t)NC * ICN * 8 * sizeof(float);      // 131,072
    if (ws_size >= prm_off + prm_bytes) {
        _Float16* xt = (_Float16*)d_ws;
        float* prm = (float*)((char*)d_ws + prm_off);
        hipMemsetAsync(d_ws, 0, xt_bytes, stream);   // zero the pad borders
        hipLaunchKernelGGL(prep_kernel, dim3((NC*ICN + 255)/256), dim3(256),
                           0, stream, geo, lin, prm);
        hipLaunchKernelGGL(transpose_pad_kernel, dim3((ICN*HW + 255)/256), dim3(256),
                           0, stream, x, xt);
        hipLaunchKernelGGL(geom_h_kernel, dim3(NC, 49), dim3(64),
                           0, stream, xt, prm, boxp, out);
    } else {
        hipLaunchKernelGGL(geom_kernel, dim3(NC, (HW + 255)/256), dim3(256),
                           0, stream, x, geo, lin, boxp, out);
    }
}